// Round 1
// 86.017 us; speedup vs baseline: 1.0177x; 1.0177x over previous
//
#include <hip/hip_runtime.h>
#include <math.h>

#define BATCH 16
#define NPRED 25000
#define MTGT  64
#define CHUNKS 32
#define PPC   800                 // preds per chunk (32*800 = 25600 >= 25000)
#define ABLK  512                 // threads per argmax block (8 waves)
#define WAVES (ABLK / 64)
#define PPW   (PPC / WAVES)       // 100 preds per wave

// ws layout (every location is plain-stored by K1 before K2 reads it —
// stream order guarantees visibility; NO zero-init required, poison-safe):
//   cand[b][chunk][t] : u64 packed (iou_bits<<32)|~n,  offset 0,   256 KB
//   focalp[b][chunk]  : float partial focal sums,      offset 256K, 2 KB
#define CAND_OFF 0
#define FOCALP_OFF (BATCH * CHUNKS * MTGT * 8)

__device__ __forceinline__ float focal_term(float x, float t) {
    // mirrors reference focal_loss elementwise (ALPHA=0.25, GAMMA=2)
    float prob = 1.0f / (1.0f + expf(-x));
    float ce = fmaxf(x, 0.0f) - x * t + log1pf(expf(-fabsf(x)));
    float p_t = prob * t + (1.0f - prob) * (1.0f - t);
    float alpha_t = 0.25f * t + 0.75f * (1.0f - t);
    p_t = fminf(fmaxf(p_t, 1e-6f), 1.0f - 1e-6f);
    float om = 1.0f - p_t;
    return alpha_t * om * om * ce;
}

__global__ __launch_bounds__(ABLK) void iou_argmax_kernel(
    const float* __restrict__ preds,    // (B, N, 5)
    const float* __restrict__ targets,  // (B, M, 4) xyxy
    unsigned long long* __restrict__ cand,  // (B, CHUNKS, M) plain store
    float* __restrict__ focalp)             // (B, CHUNKS) plain store
{
    const int b = blockIdx.y;
    const int chunk = blockIdx.x;
    const int t = threadIdx.x;
    const int lane = t & 63;
    const int w = t >> 6;

    __shared__ float4 sbox[PPC];                       // xyxy
    __shared__ float sarea[PPC];                       // precomputed pred area
    __shared__ unsigned long long comb[WAVES][MTGT];
    __shared__ float sfocal[WAVES];

    // ---- stage preds -> LDS (xyxy + area), accumulate focal(conf, 0) ----
    float fsum = 0.0f;
    for (int idx = t; idx < PPC; idx += ABLK) {
        int n = chunk * PPC + idx;
        float4 bx;
        if (n < NPRED) {
            const float* p = preds + ((long)b * NPRED + n) * 5;
            float cx = p[0], cy = p[1];
            float wd = fmaxf(p[2], 1e-4f);
            float hh = fmaxf(p[3], 1e-4f);
            bx.x = cx - wd / 2.0f;
            bx.y = cy - hh / 2.0f;
            bx.z = cx + wd / 2.0f;
            bx.w = cy + hh / 2.0f;
            fsum += focal_term(p[4], 0.0f);
        } else {
            bx = make_float4(3e8f, 3e8f, 3e8f, 3e8f);  // sentinel: inter = 0
        }
        sbox[idx] = bx;
        // reference computes area from xyxy, so derive from bx (sentinel -> 0)
        sarea[idx] = (bx.z - bx.x) * (bx.w - bx.y);
    }
    // wave-reduce focal partial
    for (int off = 32; off > 0; off >>= 1) fsum += __shfl_down(fsum, off);
    if (lane == 0) sfocal[w] = fsum;

    // ---- my target (lane = target index) ----
    const float* tg = targets + ((long)b * MTGT + lane) * 4;
    float tx1 = tg[0], ty1 = tg[1], tx2 = tg[2], ty2 = tg[3];
    float ta = (tx2 - tx1) * (ty2 - ty1);

    __syncthreads();

    // ---- wave w scans preds [w*PPW, (w+1)*PPW); lane m = its own target ----
    float best_i = 0.0f, best_d = 1.0f;
    int best_j = 0;
#pragma unroll 4
    for (int j = 0; j < PPW; j++) {
        float4 bx = sbox[w * PPW + j];                 // LDS broadcast read
        float ap = sarea[w * PPW + j];                 // precomputed area
        float ltx = fmaxf(bx.x, tx1), lty = fmaxf(bx.y, ty1);
        float rbx = fminf(bx.z, tx2), rby = fminf(bx.w, ty2);
        float inter = fmaxf(rbx - ltx, 0.0f) * fmaxf(rby - lty, 0.0f);
        float den = ap + ta - inter;
        // argmax via cross-multiply (no div); strict > keeps lowest n on ties
        bool better = (inter * best_d) > (best_i * den);
        best_i = better ? inter : best_i;
        best_d = better ? den : best_d;
        best_j = better ? j : best_j;
    }
    int best_n = chunk * PPC + w * PPW + best_j;
    float iou = best_i / best_d;  // exact IEEE div, reference-identical operands
    comb[w][lane] =
        ((unsigned long long)__float_as_uint(iou) << 32) | (unsigned int)(~best_n);

    __syncthreads();

    if (t < MTGT) {
        unsigned long long v = comb[0][t];
        for (int ww = 1; ww < WAVES; ww++) {
            unsigned long long o = comb[ww][t];
            v = (o > v) ? o : v;
        }
        cand[((long)b * CHUNKS + chunk) * MTGT + t] = v;   // plain store
    }
    if (t == 0) {
        float s = 0.0f;
        for (int ww = 0; ww < WAVES; ww++) s += sfocal[ww];
        focalp[b * CHUNKS + chunk] = s;                    // plain store
    }
}

__global__ __launch_bounds__(BATCH * 64) void finalize_kernel(
    const float* __restrict__ preds,
    const float* __restrict__ targets,
    const unsigned long long* __restrict__ cand,
    const float* __restrict__ focalp,
    float* __restrict__ out)  // written unconditionally, no pre-zero needed
{
    const int t = threadIdx.x;
    const int b = t >> 6;       // one wave per image
    const int lane = t & 63;    // lane = target index

    __shared__ float sper[BATCH];

    // ---- reduce per-chunk candidates (replaces atomicMax on zeroed gmax) ----
    const unsigned long long* cb = cand + ((long)b * CHUNKS) * MTGT + lane;
    unsigned long long packed = cb[0];
#pragma unroll
    for (int c = 1; c < CHUNKS; c++) {
        unsigned long long o = cb[(long)c * MTGT];
        packed = (o > packed) ? o : packed;
    }
    int id = (int)(~(unsigned int)packed);

    const float* tgp = targets + ((long)b * MTGT + lane) * 4;
    float x1t = tgp[0], y1t = tgp[1], x2t = tgp[2], y2t = tgp[3];

    // recompute exact pairwise IoU of (winner pred, my target) for threshold
    float x1p = 0.f, y1p = 0.f, x2p = 0.f, y2p = 0.f, cf = 0.f;
    float v = 0.0f;
    if (id >= 0 && id < NPRED) {
        const float* p = preds + ((long)b * NPRED + id) * 5;
        float cx = p[0], cy = p[1];
        float wd = fmaxf(p[2], 1e-4f);
        float hh = fmaxf(p[3], 1e-4f);
        cf = p[4];
        x1p = cx - wd / 2.0f; y1p = cy - hh / 2.0f;
        x2p = cx + wd / 2.0f; y2p = cy + hh / 2.0f;
        float ltx = fmaxf(x1p, x1t), lty = fmaxf(y1p, y1t);
        float rbx = fminf(x2p, x2t), rby = fminf(y2p, y2t);
        float inter = fmaxf(rbx - ltx, 0.0f) * fmaxf(rby - lty, 0.0f);
        float ap = (x2p - x1p) * (y2p - y1p);
        float at = (x2t - x1t) * (y2t - y1t);
        v = inter / (ap + at - inter);
    }

    // greedy match, all-register: lane m accepted iff iou>thr and pred unclaimed
    bool accepted = false;
    for (int m = 0; m < MTGT; m++) {
        float vm = __shfl(v, m);
        int im = __shfl(id, m);
        unsigned long long conflict = __ballot(accepted && (id == im));
        bool ok = (vm > 0.2f) && (conflict == 0ull);
        if (lane == m) accepted = ok;
    }

    float csum = 0.0f;
    int cnt = 0;
    // fold the per-chunk focal partials into dsum's wave reduction
    float dsum = (lane < CHUNKS) ? focalp[b * CHUNKS + lane] : 0.0f;
    if (accepted) {
        // ciou_loss, op-order per reference, EPS=1e-7
        float ltx = fmaxf(x1p, x1t), lty = fmaxf(y1p, y1t);
        float rbx = fminf(x2p, x2t), rby = fminf(y2p, y2t);
        float inter = fmaxf(rbx - ltx, 0.0f) * fmaxf(rby - lty, 0.0f);
        float uni = (x2p - x1p) * (y2p - y1p) + (x2t - x1t) * (y2t - y1t) - inter;
        float iou = inter / (uni + 1e-7f);
        float cx1 = fminf(x1p, x1t), cy1 = fminf(y1p, y1t);
        float cx2 = fmaxf(x2p, x2t), cy2 = fmaxf(y2p, y2t);
        float dx = cx2 - cx1, dy = cy2 - cy1;
        float diag = dx * dx + dy * dy + 1e-7f;
        float ex = x1p + x2p - x1t - x2t;
        float ey = y1p + y2p - y1t - y2t;
        float centers = (ex * ex + ey * ey) / 4.0f;
        float diou = 1.0f - iou + centers / diag;
        float wp = x2p - x1p, hp = y2p - y1p;
        float wt = x2t - x1t, ht = y2t - y1t;
        float dat = atanf(wt / ht) - atanf(wp / hp);
        float vv = 0.40528473f * (dat * dat);  // 4/pi^2
        float alpha = vv / (1.0f - iou + vv + 1e-7f);
        csum = diou + alpha * vv;
        cnt = 1;
        dsum += focal_term(cf, 1.0f) - focal_term(cf, 0.0f);
    }

    for (int off = 32; off > 0; off >>= 1) {
        csum += __shfl_down(csum, off);
        dsum += __shfl_down(dsum, off);
        cnt  += __shfl_down(cnt, off);
    }
    if (lane == 0) {
        float per = dsum / (float)NPRED;           // conf (focal mean)
        if (cnt > 0) per += csum / (float)cnt;     // + box loss
        sper[b] = per;
    }
    __syncthreads();
    if (t == 0) {
        float s = 0.0f;
        for (int i = 0; i < BATCH; i++) s += sper[i];
        out[0] = s / (float)BATCH;                 // direct store, no atomic
    }
}

extern "C" void kernel_launch(void* const* d_in, const int* in_sizes, int n_in,
                              void* d_out, int out_size, void* d_ws, size_t ws_size,
                              hipStream_t stream) {
    const float* preds = (const float*)d_in[0];     // (16, 25000, 5) f32
    const float* targets = (const float*)d_in[1];   // (16, 64, 4) f32
    float* out = (float*)d_out;

    unsigned long long* cand = (unsigned long long*)((char*)d_ws + CAND_OFF);
    float* focalp = (float*)((char*)d_ws + FOCALP_OFF);

    // no memsets: ws locations are written before read (stream-ordered),
    // out is overwritten unconditionally by finalize_kernel
    dim3 gridA(CHUNKS, BATCH);
    iou_argmax_kernel<<<gridA, ABLK, 0, stream>>>(preds, targets, cand, focalp);
    finalize_kernel<<<1, BATCH * 64, 0, stream>>>(preds, targets, cand, focalp, out);
}